// Round 8
// baseline (752.310 us; speedup 1.0000x reference)
//
#include <hip/hip_runtime.h>
#include <hip/hip_cooperative_groups.h>

namespace cg = cooperative_groups;

// ---------------------------------------------------------------------------
// JK-SAGE forward. bf16 features, fp32 accumulate, MFMA bf16 GEMMs.
// 4 dispatches:
//   memset(counters)
//   coop_build  (ONE cooperative kernel: cast + weight repack + bucket hist
//                -> grid.sync -> scan -> grid.sync -> partition (dual layer)
//                -> grid.sync -> per-bucket node sort (dual layer))
//   fused_layer1 (gather+GEMM)          [round-3 proven body]
//   fused_layer2 (gather+GEMM+JK out)   [round-3 proven body]
// Edge record: src | (dst&255)<<17  (requires N <= 131072; here N = 100000).
// All build phase bodies are bit-identical to the round-3 proven kernels;
// only dispatch boundaries are replaced by grid syncs. Round-7 lesson: do
// NOT split dual-layer stages into role-union chains (halves parallelism);
// round-4 lesson: never serialize contended atomics onto lane 0.
// ---------------------------------------------------------------------------

#define MAXB  512    // max buckets (N <= 131072 with 256-node buckets)
#define CAP   24     // partition LDS staging entries per bucket
#define CAPS  6144   // sort per-bucket record capacity (lambda=4096, 32 sigma)
#define PCH   384    // partition chunks per layer
#define HCH   384    // hist chunks per layer

typedef __attribute__((ext_vector_type(8))) short short8;
typedef __attribute__((ext_vector_type(4))) float floatx4;

__device__ __forceinline__ unsigned short f2b(float f) {
    unsigned u = __float_as_uint(f);
    unsigned r = (u + 0x7fffu + ((u >> 16) & 1u)) >> 16;   // RNE
    return (unsigned short)r;
}
__device__ __forceinline__ float lo2f(unsigned u) { return __uint_as_float(u << 16); }
__device__ __forceinline__ float hi2f(unsigned u) { return __uint_as_float(u & 0xffff0000u); }
__device__ __forceinline__ unsigned pack2(float a, float b) {
    return (unsigned)f2b(a) | ((unsigned)f2b(b) << 16);
}

// ---- shared-memory overlays (max 51200 B -> 3 blocks/CU)
struct PartSmem { unsigned stage[MAXB][CAP]; int lcnt[MAXB]; };                  // 51200 B
struct SortSmem { int recs[CAPS]; int sorted[CAPS]; int hcnt[256]; int hoff[256]; }; // 51200 B

// ---- round-3 proven partition body (per-thread claims + serial stores)
__device__ __forceinline__ void partition_body(const int* __restrict__ src,
        const int* __restrict__ dst, const int* __restrict__ bptr,
        int* __restrict__ gcur, int* __restrict__ part, int E, int nb,
        int chunk, int nchunks, PartSmem& s) {
    const int t = threadIdx.x;
    for (int i = t; i < nb; i += 256) s.lcnt[i] = 0;
    __syncthreads();
    const int per = (E + nchunks - 1) / nchunks;
    const int e0 = chunk * per;
    const int e1 = min(e0 + per, E);
    for (int e = e0 + t; e < e1; e += 256) {
        int d = dst[e];
        int b = d >> 8;
        unsigned rec = (unsigned)src[e] | ((unsigned)(d & 255) << 17);
        int p = atomicAdd(&s.lcnt[b], 1);
        if (p < CAP) s.stage[b][p] = rec;
        else {   // staging overflow (rare): direct global write
            int g = atomicAdd(&gcur[b], 1);
            part[bptr[b] + g] = (int)rec;
        }
    }
    __syncthreads();
    for (int b = t; b < nb; b += 256) {
        int c = s.lcnt[b]; if (c > CAP) c = CAP;
        if (c > 0) {
            int g = atomicAdd(&gcur[b], c);
            int base = bptr[b] + g;
            for (int i = 0; i < c; ++i) part[base + i] = (int)s.stage[b][i];
        }
    }
}

// ---- round-3 proven sort body: one bucket -> per-node CSR order
__device__ __forceinline__ void sort_body(const int* __restrict__ bptr,
        const int* __restrict__ part, int* __restrict__ col,
        int* __restrict__ row_ptr, int b, int nb_total, int N, int E,
        SortSmem& s) {
    const int t = threadIdx.x;
    const int beg = bptr[b], end = bptr[b + 1];
    int cnt = end - beg;
    if (cnt > CAPS) cnt = CAPS;   // statistically impossible (32 sigma margin)

    for (int i = t; i < cnt; i += 256) s.recs[i] = part[beg + i];
    s.hcnt[t] = 0;
    __syncthreads();
    for (int i = t; i < cnt; i += 256)
        atomicAdd(&s.hcnt[((unsigned)s.recs[i]) >> 17], 1);
    __syncthreads();

    int v = s.hcnt[t];
    s.hoff[t] = v;
    __syncthreads();
    for (int off = 1; off < 256; off <<= 1) {
        int y = (t >= off) ? s.hoff[t - off] : 0;
        __syncthreads();
        s.hoff[t] += y;
        __syncthreads();
    }
    int myoff = s.hoff[t] - v;   // exclusive prefix for local node t

    int row = b * 256 + t;
    if (row <= N) row_ptr[row] = beg + myoff;
    if (b == nb_total - 1 && t == 0) row_ptr[N] = E;
    __syncthreads();
    s.hoff[t] = myoff;
    s.hcnt[t] = 0;       // reuse as cursor
    __syncthreads();

    for (int i = t; i < cnt; i += 256) {
        unsigned rec = (unsigned)s.recs[i];
        int node = rec >> 17;
        int p = s.hoff[node] + atomicAdd(&s.hcnt[node], 1);
        s.sorted[p] = (int)(rec & 0x1FFFF);
    }
    __syncthreads();
    for (int i = t; i < cnt; i += 256) col[beg + i] = s.sorted[i];
}

struct BuildArgs {
    const float4* x4; uint4* xb4; long n8;
    const float* wl1; const float* wr1; const float* wl2; const float* wr2;
    const float* wo;
    unsigned short* wt1; unsigned short* wt2; unsigned short* wot;
    const int* ei1; const int* ei2;
    int* hist1; int* hist2; int* bptr1; int* bptr2;
    int* gcur1; int* gcur2; int* part1; int* part2;
    int* col1; int* col2; int* row_ptr1; int* row_ptr2;
    int N; int E; int nb;
};

// ---- ONE cooperative build kernel: cast+repack+hist | scan | partition | sort
__global__ __launch_bounds__(256)
void coop_build(BuildArgs a) {
    __shared__ alignas(16) char smem[sizeof(PartSmem)];
    cg::grid_group grid = cg::this_grid();
    const int t = threadIdx.x;
    const int nblk = (int)gridDim.x;
    const long gstart = (long)blockIdx.x * 256 + t;
    const long gstep  = (long)nblk * 256;

    // ---- phase 0a: cast x -> bf16 (grid-stride)
    for (long i = gstart; i < a.n8; i += gstep) {
        float4 va = a.x4[i * 2];
        float4 vb = a.x4[i * 2 + 1];
        uint4 o;
        o.x = pack2(va.x, va.y); o.y = pack2(va.z, va.w);
        o.z = pack2(vb.x, vb.y); o.w = pack2(vb.z, vb.w);
        a.xb4[i] = o;
    }
    // ---- phase 0b: weight repack into MFMA b-frag order (grid-stride)
    for (long i = gstart; i < 65536 + 12288; i += gstep) {
        if (i < 65536) {
            int l = (int)(i >> 15);
            int k5 = (int)(i & 32767);
            int j = k5 & 7, lane = (k5 >> 3) & 63, kb = (k5 >> 9) & 7, c = k5 >> 12;
            int k = kb * 32 + (lane >> 4) * 8 + j;
            int n = c * 16 + (lane & 15);
            const float* Wl = l ? a.wl2 : a.wl1;
            const float* Wr = l ? a.wr2 : a.wr1;
            float v = (k < 128) ? Wl[k * 128 + n] : Wr[(k - 128) * 128 + n];
            (l ? a.wt2 : a.wt1)[k5] = f2b(v);
        } else {
            int k5 = (int)(i - 65536);
            int j = k5 & 7, lane = (k5 >> 3) & 63, kb = (k5 >> 9) & 7, c = k5 >> 12;
            int k = kb * 32 + (lane >> 4) * 8 + j;
            int col = c * 16 + (lane & 15);
            float v = (col < 40) ? a.wo[k * 40 + col] : 0.0f;
            a.wot[k5] = f2b(v);
        }
    }
    // ---- phase 0c: bucket histogram, both layers (counters pre-zeroed by memset)
    {
        int* h = (int*)smem;
        for (int w = blockIdx.x; w < 2 * HCH; w += nblk) {
            const int layer = w / HCH, bx = w % HCH;
            const int* dst = (layer ? a.ei2 : a.ei1) + a.E;
            int* hist      = layer ? a.hist2 : a.hist1;
            for (int k = t; k < a.nb; k += 256) h[k] = 0;
            __syncthreads();
            for (int e = bx * 256 + t; e < a.E; e += HCH * 256)
                atomicAdd(&h[dst[e] >> 8], 1);
            __syncthreads();
            for (int k = t; k < a.nb; k += 256)
                if (h[k]) atomicAdd(&hist[k], h[k]);
            __syncthreads();
        }
    }
    grid.sync();

    // ---- phase 1: exclusive bucket scan (block 0 = layer 1, block 1 = layer 2)
    if (blockIdx.x < 2) {
        int* pair = (int*)smem;
        int* hist = blockIdx.x ? a.hist2 : a.hist1;
        int* bptr = blockIdx.x ? a.bptr2 : a.bptr1;
        int v0 = (2 * t < a.nb)     ? atomicAdd(&hist[2 * t], 0)     : 0;
        int v1 = (2 * t + 1 < a.nb) ? atomicAdd(&hist[2 * t + 1], 0) : 0;
        pair[t] = v0 + v1;
        __syncthreads();
        for (int off = 1; off < 256; off <<= 1) {
            int y = (t >= off) ? pair[t - off] : 0;
            __syncthreads();
            pair[t] += y;
            __syncthreads();
        }
        int ebase = pair[t] - (v0 + v1);
        if (2 * t < a.nb)     bptr[2 * t]     = ebase;
        if (2 * t + 1 < a.nb) bptr[2 * t + 1] = ebase + v0;
        if (t == 0) bptr[a.nb] = a.E;
        __threadfence();
    }
    grid.sync();

    // ---- phase 2: partition edges into bucket regions, both layers
    for (int w = blockIdx.x; w < 2 * PCH; w += nblk) {
        const int layer = w / PCH, chunk = w % PCH;
        const int* src = layer ? a.ei2 : a.ei1;
        partition_body(src, src + a.E,
                       layer ? a.bptr2 : a.bptr1,
                       layer ? a.gcur2 : a.gcur1,
                       layer ? a.part2 : a.part1,
                       a.E, a.nb, chunk, PCH,
                       *reinterpret_cast<PartSmem*>(smem));
        __syncthreads();
    }
    __threadfence();
    grid.sync();

    // ---- phase 3: per-bucket node sort -> CSR, both layers
    for (int w = blockIdx.x; w < 2 * a.nb; w += nblk) {
        const int layer = (w >= a.nb) ? 1 : 0;
        const int b = w - layer * a.nb;
        sort_body(layer ? a.bptr2 : a.bptr1,
                  layer ? a.part2 : a.part1,
                  layer ? a.col2 : a.col1,
                  layer ? a.row_ptr2 : a.row_ptr1,
                  b, a.nb, a.N, a.E,
                  *reinterpret_cast<SortSmem*>(smem));
        __syncthreads();
    }
}

// ---- proven CSR gather body: mean of xb[col[...]] into fp32 acc[8].
// 16 lanes/node, 8 row-loads in flight, col prefetch for next chunk.
__device__ __forceinline__ void gather_node(const uint4* __restrict__ xb,
                                            const int* __restrict__ col,
                                            int beg, int end, int lane,
                                            float acc[8]) {
    int e = beg;
    if (e + 8 <= end) {
        int cidx[8];
#pragma unroll
        for (int q = 0; q < 8; ++q) cidx[q] = col[e + q];
        for (;;) {
            uint4 v[8];
#pragma unroll
            for (int q = 0; q < 8; ++q) v[q] = xb[(size_t)cidx[q] * 16 + lane];
            e += 8;
            const bool more = (e + 8 <= end);
            if (more) {
#pragma unroll
                for (int q = 0; q < 8; ++q) cidx[q] = col[e + q];
            }
#pragma unroll
            for (int q = 0; q < 8; ++q) {
                acc[0] += lo2f(v[q].x); acc[1] += hi2f(v[q].x);
                acc[2] += lo2f(v[q].y); acc[3] += hi2f(v[q].y);
                acc[4] += lo2f(v[q].z); acc[5] += hi2f(v[q].z);
                acc[6] += lo2f(v[q].w); acc[7] += hi2f(v[q].w);
            }
            if (!more) break;
        }
    }
    for (; e + 3 < end; e += 4) {
        uint4 v[4];
#pragma unroll
        for (int q = 0; q < 4; ++q) v[q] = xb[(size_t)col[e + q] * 16 + lane];
#pragma unroll
        for (int q = 0; q < 4; ++q) {
            acc[0] += lo2f(v[q].x); acc[1] += hi2f(v[q].x);
            acc[2] += lo2f(v[q].y); acc[3] += hi2f(v[q].y);
            acc[4] += lo2f(v[q].z); acc[5] += hi2f(v[q].z);
            acc[6] += lo2f(v[q].w); acc[7] += hi2f(v[q].w);
        }
    }
    for (; e < end; ++e) {
        uint4 v0 = xb[(size_t)col[e] * 16 + lane];
        acc[0] += lo2f(v0.x); acc[1] += hi2f(v0.x);
        acc[2] += lo2f(v0.y); acc[3] += hi2f(v0.y);
        acc[4] += lo2f(v0.z); acc[5] += hi2f(v0.z);
        acc[6] += lo2f(v0.w); acc[7] += hi2f(v0.w);
    }
    float inv = 1.0f / fmaxf((float)(end - beg), 1.0f);
#pragma unroll
    for (int j = 0; j < 8; ++j) acc[j] *= inv;
}

// LDS tile: 16 rows x 16 uint4, slot = row*16 + (col4 ^ (row&7))  (bank swizzle)
#define LDS_SLOT(row, col4) ((row) * 16 + ((col4) ^ ((row) & 7)))

// ---- fused layer 1: gather (tile of 16 consecutive nodes -> LDS) + GEMM -> h1b
__global__ __launch_bounds__(256)
void fused_layer1(const uint4* __restrict__ xb, const int* __restrict__ row_ptr,
                  const int* __restrict__ col,
                  const unsigned short* __restrict__ Wt,  // frag-order [8][8][64][8]
                  const float* __restrict__ bias,
                  unsigned short* __restrict__ Hb, int N) {
    __shared__ uint4 lds[16 * 16];
    const int t = threadIdx.x;
    {   // gather phase: node = base + t/16, lane = t%16 (proven kernel)
        const int lrow = t >> 4;
        const int lane = t & 15;
        const int node = blockIdx.x * 16 + lrow;
        float acc[8];
#pragma unroll
        for (int j = 0; j < 8; ++j) acc[j] = 0.0f;
        if (node < N)
            gather_node(xb, col, row_ptr[node], row_ptr[node + 1], lane, acc);
        uint4 o;
        o.x = pack2(acc[0], acc[1]); o.y = pack2(acc[2], acc[3]);
        o.z = pack2(acc[4], acc[5]); o.w = pack2(acc[6], acc[7]);
        lds[LDS_SLOT(lrow, lane)] = o;
    }
    __syncthreads();

    // GEMM phase: wave w owns col-tiles {2w, 2w+1}; A rows 0..15 shared.
    const int wave = t >> 6;
    const int lane = t & 63;
    const int quad = lane >> 4;
    const int l16  = lane & 15;
    const int rowbase = blockIdx.x * 16;

    floatx4 acc2[2] = {(floatx4){0.f,0.f,0.f,0.f}, (floatx4){0.f,0.f,0.f,0.f}};
    int arow = rowbase + l16; if (arow >= N) arow = N - 1;
    const unsigned short* Xs = (const unsigned short*)xb;
    const size_t aoff = (size_t)arow * 128 + quad * 8;

#pragma unroll
    for (int kb = 0; kb < 8; ++kb) {
        short8 a;
        if (kb < 4)
            a = __builtin_bit_cast(short8, lds[LDS_SLOT(l16, quad + (kb & 3) * 4)]);
        else
            a = __builtin_bit_cast(short8, *(const uint4*)(Xs + aoff + (kb & 3) * 32));
#pragma unroll
        for (int cc = 0; cc < 2; ++cc) {
            const int c = wave * 2 + cc;
            short8 b = __builtin_bit_cast(short8,
                *(const uint4*)(Wt + (size_t)(((c * 8 + kb) * 64 + lane) * 8)));
            acc2[cc] = __builtin_amdgcn_mfma_f32_16x16x32_bf16(a, b, acc2[cc], 0, 0, 0);
        }
    }

#pragma unroll
    for (int cc = 0; cc < 2; ++cc) {
        const int c = wave * 2 + cc;
        const float bc = bias[c * 16 + l16];
#pragma unroll
        for (int i = 0; i < 4; ++i) {
            int row = rowbase + quad * 4 + i;
            if (row < N)
                Hb[(size_t)row * 128 + c * 16 + l16] = f2b(fmaxf(acc2[cc][i] + bc, 0.f));
        }
    }
}

// ---- fused layer 2: gather + GEMM + JK out. h2 lives only in regs/LDS.
__global__ __launch_bounds__(256)
void fused_layer2(const uint4* __restrict__ h1b4, const int* __restrict__ row_ptr,
                  const int* __restrict__ col,
                  const unsigned short* __restrict__ Wt,   // [8][8][64][8]
                  const float* __restrict__ bias,
                  const unsigned short* __restrict__ Wot,  // [3][8][64][8]; kb<4 = h1, kb>=4 = h2
                  const float* __restrict__ bo,
                  float* __restrict__ out, int N) {
    __shared__ uint4 lds[16 * 16];
    const int t = threadIdx.x;
    {   // gather phase (source = h1b)
        const int lrow = t >> 4;
        const int lane = t & 15;
        const int node = blockIdx.x * 16 + lrow;
        float acc[8];
#pragma unroll
        for (int j = 0; j < 8; ++j) acc[j] = 0.0f;
        if (node < N)
            gather_node(h1b4, col, row_ptr[node], row_ptr[node + 1], lane, acc);
        uint4 o;
        o.x = pack2(acc[0], acc[1]); o.y = pack2(acc[2], acc[3]);
        o.z = pack2(acc[4], acc[5]); o.w = pack2(acc[6], acc[7]);
        lds[LDS_SLOT(lrow, lane)] = o;
    }
    __syncthreads();

    const int wave = t >> 6;
    const int lane = t & 63;
    const int quad = lane >> 4;
    const int l16  = lane & 15;
    const int rowbase = blockIdx.x * 16;

    floatx4 acc2[2] = {(floatx4){0.f,0.f,0.f,0.f}, (floatx4){0.f,0.f,0.f,0.f}};
    floatx4 accO    = (floatx4){0.f,0.f,0.f,0.f};
    int arow = rowbase + l16; if (arow >= N) arow = N - 1;
    const unsigned short* H1s = (const unsigned short*)h1b4;
    const size_t aoff = (size_t)arow * 128 + quad * 8;

#pragma unroll
    for (int kb = 0; kb < 8; ++kb) {
        short8 a;
        if (kb < 4)
            a = __builtin_bit_cast(short8, lds[LDS_SLOT(l16, quad + (kb & 3) * 4)]);
        else
            a = __builtin_bit_cast(short8, *(const uint4*)(H1s + aoff + (kb & 3) * 32));
#pragma unroll
        for (int cc = 0; cc < 2; ++cc) {
            const int c = wave * 2 + cc;
            short8 b = __builtin_bit_cast(short8,
                *(const uint4*)(Wt + (size_t)(((c * 8 + kb) * 64 + lane) * 8)));
            acc2[cc] = __builtin_amdgcn_mfma_f32_16x16x32_bf16(a, b, acc2[cc], 0, 0, 0);
        }
        if (kb >= 4 && wave < 3) {   // out += h1 @ WotTop (reuse live h1 frags)
            short8 b = __builtin_bit_cast(short8,
                *(const uint4*)(Wot + (size_t)(((wave * 8 + (kb - 4)) * 64 + lane) * 8)));
            accO = __builtin_amdgcn_mfma_f32_16x16x32_bf16(a, b, accO, 0, 0, 0);
        }
    }

    __syncthreads();   // all agg-frag reads done before overwriting LDS with h2
    {   // h2 = relu(acc2 + bias) -> LDS (bf16, same swizzled layout)
        unsigned short* lds16 = (unsigned short*)lds;
#pragma unroll
        for (int cc = 0; cc < 2; ++cc) {
            const int c = wave * 2 + cc;
            const float bc = bias[c * 16 + l16];
            const int colc = c * 16 + l16;
            const int col4 = colc >> 3;
#pragma unroll
            for (int i = 0; i < 4; ++i) {
                const int lrow = quad * 4 + i;
                lds16[LDS_SLOT(lrow, col4) * 8 + (colc & 7)] =
                    f2b(fmaxf(acc2[cc][i] + bc, 0.f));
            }
        }
    }
    __syncthreads();

    if (wave < 3) {    // out += h2 @ WotBot ; write fp32 out (40 cols)
#pragma unroll
        for (int kh = 0; kh < 4; ++kh) {
            short8 a = __builtin_bit_cast(short8, lds[LDS_SLOT(l16, quad + kh * 4)]);
            short8 b = __builtin_bit_cast(short8,
                *(const uint4*)(Wot + (size_t)(((wave * 8 + 4 + kh) * 64 + lane) * 8)));
            accO = __builtin_amdgcn_mfma_f32_16x16x32_bf16(a, b, accO, 0, 0, 0);
        }
        const int colc = wave * 16 + l16;
        if (colc < 40) {
            const float bco = bo[colc];
#pragma unroll
            for (int i = 0; i < 4; ++i) {
                int row = rowbase + quad * 4 + i;
                if (row < N) out[(size_t)row * 40 + colc] = accO[i] + bco;
            }
        }
    }
}

extern "C" void kernel_launch(void* const* d_in, const int* in_sizes, int n_in,
                              void* d_out, int out_size, void* d_ws, size_t ws_size,
                              hipStream_t stream) {
    const float* x     = (const float*)d_in[0];
    const int*   ei1   = (const int*)d_in[1];
    const int*   ei2   = (const int*)d_in[2];
    const float* wl1   = (const float*)d_in[3];
    const float* wr1   = (const float*)d_in[4];
    const float* b1    = (const float*)d_in[5];
    const float* wl2   = (const float*)d_in[6];
    const float* wr2   = (const float*)d_in[7];
    const float* b2    = (const float*)d_in[8];
    const float* w_out = (const float*)d_in[9];
    const float* b_out = (const float*)d_in[10];

    const int N  = in_sizes[0] / 128;
    const int E  = in_sizes[1] / 2;
    const int nb = (N + 255) >> 8;   // buckets of 256 dst nodes (<= MAXB)

    // ---- workspace (ints): [hist1|gcur1|hist2|gcur2]=2048 | bptr1 | bptr2 |
    //      row_ptr1 | row_ptr2 | part1 | col1 | part2 | col2 | bf16 arrays
    int* hist1    = (int*)d_ws;
    int* gcur1    = hist1 + 512;
    int* hist2    = gcur1 + 512;
    int* gcur2    = hist2 + 512;
    int* bptr1    = gcur2 + 512;
    int* bptr2    = bptr1 + 513;
    int* row_ptr1 = bptr2 + 513;
    int* row_ptr2 = row_ptr1 + (N + 1);
    int* part1    = row_ptr2 + (N + 1);
    int* col1     = part1 + E;
    int* part2    = col1 + E;
    int* col2     = part2 + E;
    size_t int_cnt = (size_t)(2048 + 1026 + 2 * (N + 1)) + (size_t)4 * E;
    int_cnt = (int_cnt + 3) & ~(size_t)3;                 // 16 B align
    unsigned short* xb   = (unsigned short*)((int*)d_ws + int_cnt);
    unsigned short* h1b  = xb  + (size_t)N * 128;
    unsigned short* wt1  = h1b + (size_t)N * 128;
    unsigned short* wt2  = wt1 + 32768;
    unsigned short* wot  = wt2 + 32768;

    const long n8         = (long)N * 128 / 8;
    const int tile_blocks = (N + 15) / 16;

    // cooperative grid size: min(co-resident capacity, 768) [cached]
    static int coop_grid = 0;
    if (coop_grid == 0) {
        int occ = 0;
        hipOccupancyMaxActiveBlocksPerMultiprocessor(
            &occ, (const void*)coop_build, 256, 0);
        int dev = 0, cus = 0;
        hipGetDevice(&dev);
        hipDeviceGetAttribute(&cus, hipDeviceAttributeMultiprocessorCount, dev);
        long cap = (long)occ * (long)cus;
        coop_grid = (int)(cap < 768 ? cap : 768);
        if (coop_grid < 2) coop_grid = 2;
    }

    hipMemsetAsync(hist1, 0, 2048 * sizeof(int), stream);

    BuildArgs ba;
    ba.x4 = (const float4*)x; ba.xb4 = (uint4*)xb; ba.n8 = n8;
    ba.wl1 = wl1; ba.wr1 = wr1; ba.wl2 = wl2; ba.wr2 = wr2; ba.wo = w_out;
    ba.wt1 = wt1; ba.wt2 = wt2; ba.wot = wot;
    ba.ei1 = ei1; ba.ei2 = ei2;
    ba.hist1 = hist1; ba.hist2 = hist2; ba.bptr1 = bptr1; ba.bptr2 = bptr2;
    ba.gcur1 = gcur1; ba.gcur2 = gcur2; ba.part1 = part1; ba.part2 = part2;
    ba.col1 = col1; ba.col2 = col2; ba.row_ptr1 = row_ptr1; ba.row_ptr2 = row_ptr2;
    ba.N = N; ba.E = E; ba.nb = nb;

    void* params[] = { &ba };
    hipLaunchCooperativeKernel((const void*)coop_build, dim3(coop_grid),
                               dim3(256), params, 0, stream);

    fused_layer1<<<tile_blocks, 256, 0, stream>>>(
        (const uint4*)xb, row_ptr1, col1, wt1, b1, h1b, N);
    fused_layer2<<<tile_blocks, 256, 0, stream>>>(
        (const uint4*)h1b, row_ptr2, col2, wt2, b2, wot, b_out,
        (float*)d_out, N);
}

// Round 9
// 411.820 us; speedup vs baseline: 1.8268x; 1.8268x over previous
//
#include <hip/hip_runtime.h>

// ---------------------------------------------------------------------------
// JK-SAGE forward. bf16 features, fp32 accumulate, MFMA bf16 GEMMs.
// FINAL (restored round-3 optimum + neutral fused scan). 5 dispatches + memset:
//   memset(counters)
//   prep_hist    : cast + weight repack + bucket hist + last-block fused scan
//   partition_edges2 (dim3(384,2))  [round-3 exact body, serial flush]
//   node_sort2       (dim3(nb,2))   [round-3 exact 256-bin counting sort]
//   fused_layer1 (gather+GEMM) ; fused_layer2 (gather+GEMM+JK out)
// Edge record: src | (dst&255)<<17  (requires N <= 131072; here N = 100000).
// Session ledger (why this shape):
//  - gather: 3.6-3.7 TB/s, FETCH ~268 MB -- invariant across 5 schedules;
//    random 256-B row gather ceiling of the L2/L3 path. Not improvable by
//    ordering (r6), degree-perm (r5), or edge-parallel LDS atomics (r1).
//  - build: role-union chains (r7, +48us), cooperative single-kernel (r8,
//    +370us), 16K-bin sort (r6, +75us), lane-0 serial flush (r4, +570us)
//    ALL regressed. Plain dual-layer dispatches win.
// ---------------------------------------------------------------------------

#define MAXB  512    // max buckets (N <= 131072 with 256-node buckets)
#define CAP   24     // partition LDS staging entries per bucket
#define CAPS  6144   // node_sort per-bucket record capacity (lambda=4096, 32 sigma)
#define PBLK  384    // partition grid (per layer)

typedef __attribute__((ext_vector_type(8))) short short8;
typedef __attribute__((ext_vector_type(4))) float floatx4;

__device__ __forceinline__ unsigned short f2b(float f) {
    unsigned u = __float_as_uint(f);
    unsigned r = (u + 0x7fffu + ((u >> 16) & 1u)) >> 16;   // RNE
    return (unsigned short)r;
}
__device__ __forceinline__ float lo2f(unsigned u) { return __uint_as_float(u << 16); }
__device__ __forceinline__ float hi2f(unsigned u) { return __uint_as_float(u & 0xffff0000u); }
__device__ __forceinline__ unsigned pack2(float a, float b) {
    return (unsigned)f2b(a) | ((unsigned)f2b(b) << 16);
}

// ---- fused one-time prep: cast x -> bf16, repack weights, bucket histogram,
//      and (in the last hist block to finish) the bucket exclusive scan.
__global__ __launch_bounds__(256)
void prep_hist(const float4* __restrict__ x4, uint4* __restrict__ xb4, long n8,
               const float* __restrict__ wl1, const float* __restrict__ wr1,
               const float* __restrict__ wl2, const float* __restrict__ wr2,
               const float* __restrict__ wo,
               unsigned short* __restrict__ wt1, unsigned short* __restrict__ wt2,
               unsigned short* __restrict__ wot,
               const int* __restrict__ dst1, const int* __restrict__ dst2,
               int* __restrict__ hist1, int* __restrict__ hist2,
               int* __restrict__ bptr1, int* __restrict__ bptr2,
               int* __restrict__ done, int E, int nb) {
    long i = (long)blockIdx.x * 256 + threadIdx.x;
    if (i < n8) {                                        // cast 8 floats -> bf16
        float4 a = x4[i * 2];
        float4 b = x4[i * 2 + 1];
        uint4 o;
        o.x = pack2(a.x, a.y); o.y = pack2(a.z, a.w);
        o.z = pack2(b.x, b.y); o.w = pack2(b.z, b.w);
        xb4[i] = o;
    }
    if (i < 65536) {   // layer weights into MFMA b-frag order
        int l = (int)(i >> 15);
        int k5 = (int)(i & 32767);
        int j = k5 & 7, lane = (k5 >> 3) & 63, kb = (k5 >> 9) & 7, c = k5 >> 12;
        int k = kb * 32 + (lane >> 4) * 8 + j;
        int n = c * 16 + (lane & 15);
        const float* Wl = l ? wl2 : wl1;
        const float* Wr = l ? wr2 : wr1;
        float v = (k < 128) ? Wl[k * 128 + n] : Wr[(k - 128) * 128 + n];
        (l ? wt2 : wt1)[k5] = f2b(v);
    } else if (i < 65536 + 12288) {
        int k5 = (int)(i - 65536);
        int j = k5 & 7, lane = (k5 >> 3) & 63, kb = (k5 >> 9) & 7, c = k5 >> 12;
        int k = kb * 32 + (lane >> 4) * 8 + j;
        int col = c * 16 + (lane & 15);
        float v = (col < 40) ? wo[k * 40 + col] : 0.0f;
        wot[k5] = f2b(v);
    }
    // ---- bucket histogram (blocks 0..511; counters pre-zeroed by memset)
    __shared__ int h[MAXB];
    __shared__ int sticket;
    if (blockIdx.x < 512) {
        const int layer = blockIdx.x >> 8;
        const int bx    = blockIdx.x & 255;
        const int* dst  = layer ? dst2 : dst1;
        int* hist       = layer ? hist2 : hist1;
        for (int k = threadIdx.x; k < nb; k += 256) h[k] = 0;
        __syncthreads();
        for (int e = bx * 256 + threadIdx.x; e < E; e += 256 * 256)
            atomicAdd(&h[dst[e] >> 8], 1);
        __syncthreads();
        for (int k = threadIdx.x; k < nb; k += 256)
            if (h[k]) atomicAdd(&hist[k], h[k]);
        // last hist block to finish performs the exclusive scan (both layers)
        __threadfence();
        if (threadIdx.x == 0) sticket = atomicAdd(done, 1);
        __syncthreads();
        if (sticket == 511) {
            int* pair = h;            // reuse (h's hist role is complete)
            const int tt = threadIdx.x;
            for (int l = 0; l < 2; ++l) {
                int* hist = l ? hist2 : hist1;
                int* bptr = l ? bptr2 : bptr1;
                // atomic reads: hist was written by device-scope atomics from
                // other blocks (possibly other XCDs) within this kernel.
                int v0 = (2 * tt < nb)     ? atomicAdd(&hist[2 * tt], 0)     : 0;
                int v1 = (2 * tt + 1 < nb) ? atomicAdd(&hist[2 * tt + 1], 0) : 0;
                pair[tt] = v0 + v1;
                __syncthreads();
                for (int off = 1; off < 256; off <<= 1) {
                    int y = (tt >= off) ? pair[tt - off] : 0;
                    __syncthreads();
                    pair[tt] += y;
                    __syncthreads();
                }
                int ebase = pair[tt] - (v0 + v1);
                if (2 * tt < nb)     bptr[2 * tt]     = ebase;
                if (2 * tt + 1 < nb) bptr[2 * tt + 1] = ebase + v0;
                if (tt == 0) bptr[nb] = E;
                __syncthreads();
            }
        }
    }
}

// ---- partition edges into bucket regions with LDS chunk staging; dual layer
//      (round-3 exact: per-thread claims + serial per-thread stores)
__global__ __launch_bounds__(256)
void partition_edges2(const int* __restrict__ ei1, const int* __restrict__ ei2,
                      const int* __restrict__ bptr1, const int* __restrict__ bptr2,
                      int* __restrict__ gcur1, int* __restrict__ gcur2,
                      int* __restrict__ part1, int* __restrict__ part2,
                      int E, int nb) {
    __shared__ unsigned stage[MAXB][CAP];
    __shared__ int lcnt[MAXB];
    const int* src  = blockIdx.y ? ei2 : ei1;
    const int* dst  = src + E;
    const int* bptr = blockIdx.y ? bptr2 : bptr1;
    int* gcur       = blockIdx.y ? gcur2 : gcur1;
    int* part       = blockIdx.y ? part2 : part1;
    const int t = threadIdx.x;
    for (int i = t; i < nb; i += 256) lcnt[i] = 0;
    __syncthreads();
    const int per = (E + gridDim.x - 1) / gridDim.x;
    const int e0 = blockIdx.x * per;
    const int e1 = min(e0 + per, E);
    for (int e = e0 + t; e < e1; e += 256) {
        int d = dst[e];
        int b = d >> 8;
        unsigned rec = (unsigned)src[e] | ((unsigned)(d & 255) << 17);
        int p = atomicAdd(&lcnt[b], 1);
        if (p < CAP) stage[b][p] = rec;
        else {   // staging overflow (rare): direct global write
            int g = atomicAdd(&gcur[b], 1);
            part[bptr[b] + g] = (int)rec;
        }
    }
    __syncthreads();
    for (int b = t; b < nb; b += 256) {
        int c = lcnt[b]; if (c > CAP) c = CAP;
        if (c > 0) {
            int g = atomicAdd(&gcur[b], c);
            int base = bptr[b] + g;
            for (int i = 0; i < c; ++i) part[base + i] = (int)stage[b][i];
        }
    }
}

// ---- per-bucket counting sort -> per-node CSR order; dual layer (round-3 exact)
__global__ __launch_bounds__(256)
void node_sort2(const int* __restrict__ bptr1, const int* __restrict__ bptr2,
                const int* __restrict__ part1, const int* __restrict__ part2,
                int* __restrict__ col1, int* __restrict__ col2,
                int* __restrict__ row_ptr1, int* __restrict__ row_ptr2,
                int N, int E) {
    __shared__ int recs[CAPS];
    __shared__ int sorted[CAPS];
    __shared__ int hcnt[256];
    __shared__ int hoff[256];
    const int* bptr = blockIdx.y ? bptr2 : bptr1;
    const int* part = blockIdx.y ? part2 : part1;
    int* col        = blockIdx.y ? col2 : col1;
    int* row_ptr    = blockIdx.y ? row_ptr2 : row_ptr1;
    const int b = blockIdx.x, t = threadIdx.x;
    const int beg = bptr[b], end = bptr[b + 1];
    int cnt = end - beg;
    if (cnt > CAPS) cnt = CAPS;   // statistically impossible (32 sigma margin)

    for (int i = t; i < cnt; i += 256) recs[i] = part[beg + i];
    hcnt[t] = 0;
    __syncthreads();
    for (int i = t; i < cnt; i += 256)
        atomicAdd(&hcnt[((unsigned)recs[i]) >> 17], 1);
    __syncthreads();

    int v = hcnt[t];
    hoff[t] = v;
    __syncthreads();
    for (int off = 1; off < 256; off <<= 1) {
        int y = (t >= off) ? hoff[t - off] : 0;
        __syncthreads();
        hoff[t] += y;
        __syncthreads();
    }
    int myoff = hoff[t] - v;   // exclusive prefix for local node t

    int row = b * 256 + t;
    if (row <= N) row_ptr[row] = beg + myoff;
    if (b == gridDim.x - 1 && t == 0) row_ptr[N] = E;
    __syncthreads();
    hoff[t] = myoff;
    hcnt[t] = 0;       // reuse as cursor
    __syncthreads();

    for (int i = t; i < cnt; i += 256) {
        unsigned rec = (unsigned)recs[i];
        int node = rec >> 17;
        int p = hoff[node] + atomicAdd(&hcnt[node], 1);
        sorted[p] = (int)(rec & 0x1FFFF);
    }
    __syncthreads();
    for (int i = t; i < cnt; i += 256) col[beg + i] = sorted[i];
}

// ---- proven CSR gather body: mean of xb[col[...]] into fp32 acc[8].
// 16 lanes/node, 8 row-loads in flight, col prefetch for next chunk.
__device__ __forceinline__ void gather_node(const uint4* __restrict__ xb,
                                            const int* __restrict__ col,
                                            int beg, int end, int lane,
                                            float acc[8]) {
    int e = beg;
    if (e + 8 <= end) {
        int cidx[8];
#pragma unroll
        for (int q = 0; q < 8; ++q) cidx[q] = col[e + q];
        for (;;) {
            uint4 v[8];
#pragma unroll
            for (int q = 0; q < 8; ++q) v[q] = xb[(size_t)cidx[q] * 16 + lane];
            e += 8;
            const bool more = (e + 8 <= end);
            if (more) {
#pragma unroll
                for (int q = 0; q < 8; ++q) cidx[q] = col[e + q];
            }
#pragma unroll
            for (int q = 0; q < 8; ++q) {
                acc[0] += lo2f(v[q].x); acc[1] += hi2f(v[q].x);
                acc[2] += lo2f(v[q].y); acc[3] += hi2f(v[q].y);
                acc[4] += lo2f(v[q].z); acc[5] += hi2f(v[q].z);
                acc[6] += lo2f(v[q].w); acc[7] += hi2f(v[q].w);
            }
            if (!more) break;
        }
    }
    for (; e + 3 < end; e += 4) {
        uint4 v[4];
#pragma unroll
        for (int q = 0; q < 4; ++q) v[q] = xb[(size_t)col[e + q] * 16 + lane];
#pragma unroll
        for (int q = 0; q < 4; ++q) {
            acc[0] += lo2f(v[q].x); acc[1] += hi2f(v[q].x);
            acc[2] += lo2f(v[q].y); acc[3] += hi2f(v[q].y);
            acc[4] += lo2f(v[q].z); acc[5] += hi2f(v[q].z);
            acc[6] += lo2f(v[q].w); acc[7] += hi2f(v[q].w);
        }
    }
    for (; e < end; ++e) {
        uint4 v0 = xb[(size_t)col[e] * 16 + lane];
        acc[0] += lo2f(v0.x); acc[1] += hi2f(v0.x);
        acc[2] += lo2f(v0.y); acc[3] += hi2f(v0.y);
        acc[4] += lo2f(v0.z); acc[5] += hi2f(v0.z);
        acc[6] += lo2f(v0.w); acc[7] += hi2f(v0.w);
    }
    float inv = 1.0f / fmaxf((float)(end - beg), 1.0f);
#pragma unroll
    for (int j = 0; j < 8; ++j) acc[j] *= inv;
}

// LDS tile: 16 rows x 16 uint4, slot = row*16 + (col4 ^ (row&7))  (bank swizzle)
#define LDS_SLOT(row, col4) ((row) * 16 + ((col4) ^ ((row) & 7)))

// ---- fused layer 1: gather (tile of 16 consecutive nodes -> LDS) + GEMM -> h1b
__global__ __launch_bounds__(256)
void fused_layer1(const uint4* __restrict__ xb, const int* __restrict__ row_ptr,
                  const int* __restrict__ col,
                  const unsigned short* __restrict__ Wt,  // frag-order [8][8][64][8]
                  const float* __restrict__ bias,
                  unsigned short* __restrict__ Hb, int N) {
    __shared__ uint4 lds[16 * 16];
    const int t = threadIdx.x;
    {   // gather phase: node = base + t/16, lane = t%16 (proven kernel)
        const int lrow = t >> 4;
        const int lane = t & 15;
        const int node = blockIdx.x * 16 + lrow;
        float acc[8];
#pragma unroll
        for (int j = 0; j < 8; ++j) acc[j] = 0.0f;
        if (node < N)
            gather_node(xb, col, row_ptr[node], row_ptr[node + 1], lane, acc);
        uint4 o;
        o.x = pack2(acc[0], acc[1]); o.y = pack2(acc[2], acc[3]);
        o.z = pack2(acc[4], acc[5]); o.w = pack2(acc[6], acc[7]);
        lds[LDS_SLOT(lrow, lane)] = o;
    }
    __syncthreads();

    // GEMM phase: wave w owns col-tiles {2w, 2w+1}; A rows 0..15 shared.
    const int wave = t >> 6;
    const int lane = t & 63;
    const int quad = lane >> 4;
    const int l16  = lane & 15;
    const int rowbase = blockIdx.x * 16;

    floatx4 acc2[2] = {(floatx4){0.f,0.f,0.f,0.f}, (floatx4){0.f,0.f,0.f,0.f}};
    int arow = rowbase + l16; if (arow >= N) arow = N - 1;
    const unsigned short* Xs = (const unsigned short*)xb;
    const size_t aoff = (size_t)arow * 128 + quad * 8;

#pragma unroll
    for (int kb = 0; kb < 8; ++kb) {
        short8 a;
        if (kb < 4)
            a = __builtin_bit_cast(short8, lds[LDS_SLOT(l16, quad + (kb & 3) * 4)]);
        else
            a = __builtin_bit_cast(short8, *(const uint4*)(Xs + aoff + (kb & 3) * 32));
#pragma unroll
        for (int cc = 0; cc < 2; ++cc) {
            const int c = wave * 2 + cc;
            short8 b = __builtin_bit_cast(short8,
                *(const uint4*)(Wt + (size_t)(((c * 8 + kb) * 64 + lane) * 8)));
            acc2[cc] = __builtin_amdgcn_mfma_f32_16x16x32_bf16(a, b, acc2[cc], 0, 0, 0);
        }
    }

#pragma unroll
    for (int cc = 0; cc < 2; ++cc) {
        const int c = wave * 2 + cc;
        const float bc = bias[c * 16 + l16];
#pragma unroll
        for (int i = 0; i < 4; ++i) {
            int row = rowbase + quad * 4 + i;
            if (row < N)
                Hb[(size_t)row * 128 + c * 16 + l16] = f2b(fmaxf(acc2[cc][i] + bc, 0.f));
        }
    }
}

// ---- fused layer 2: gather + GEMM + JK out. h2 lives only in regs/LDS.
__global__ __launch_bounds__(256)
void fused_layer2(const uint4* __restrict__ h1b4, const int* __restrict__ row_ptr,
                  const int* __restrict__ col,
                  const unsigned short* __restrict__ Wt,   // [8][8][64][8]
                  const float* __restrict__ bias,
                  const unsigned short* __restrict__ Wot,  // [3][8][64][8]; kb<4 = h1, kb>=4 = h2
                  const float* __restrict__ bo,
                  float* __restrict__ out, int N) {
    __shared__ uint4 lds[16 * 16];
    const int t = threadIdx.x;
    {   // gather phase (source = h1b)
        const int lrow = t >> 4;
        const int lane = t & 15;
        const int node = blockIdx.x * 16 + lrow;
        float acc[8];
#pragma unroll
        for (int j = 0; j < 8; ++j) acc[j] = 0.0f;
        if (node < N)
            gather_node(h1b4, col, row_ptr[node], row_ptr[node + 1], lane, acc);
        uint4 o;
        o.x = pack2(acc[0], acc[1]); o.y = pack2(acc[2], acc[3]);
        o.z = pack2(acc[4], acc[5]); o.w = pack2(acc[6], acc[7]);
        lds[LDS_SLOT(lrow, lane)] = o;
    }
    __syncthreads();

    const int wave = t >> 6;
    const int lane = t & 63;
    const int quad = lane >> 4;
    const int l16  = lane & 15;
    const int rowbase = blockIdx.x * 16;

    floatx4 acc2[2] = {(floatx4){0.f,0.f,0.f,0.f}, (floatx4){0.f,0.f,0.f,0.f}};
    floatx4 accO    = (floatx4){0.f,0.f,0.f,0.f};
    int arow = rowbase + l16; if (arow >= N) arow = N - 1;
    const unsigned short* H1s = (const unsigned short*)h1b4;
    const size_t aoff = (size_t)arow * 128 + quad * 8;

#pragma unroll
    for (int kb = 0; kb < 8; ++kb) {
        short8 a;
        if (kb < 4)
            a = __builtin_bit_cast(short8, lds[LDS_SLOT(l16, quad + (kb & 3) * 4)]);
        else
            a = __builtin_bit_cast(short8, *(const uint4*)(H1s + aoff + (kb & 3) * 32));
#pragma unroll
        for (int cc = 0; cc < 2; ++cc) {
            const int c = wave * 2 + cc;
            short8 b = __builtin_bit_cast(short8,
                *(const uint4*)(Wt + (size_t)(((c * 8 + kb) * 64 + lane) * 8)));
            acc2[cc] = __builtin_amdgcn_mfma_f32_16x16x32_bf16(a, b, acc2[cc], 0, 0, 0);
        }
        if (kb >= 4 && wave < 3) {   // out += h1 @ WotTop (reuse live h1 frags)
            short8 b = __builtin_bit_cast(short8,
                *(const uint4*)(Wot + (size_t)(((wave * 8 + (kb - 4)) * 64 + lane) * 8)));
            accO = __builtin_amdgcn_mfma_f32_16x16x32_bf16(a, b, accO, 0, 0, 0);
        }
    }

    __syncthreads();   // all agg-frag reads done before overwriting LDS with h2
    {   // h2 = relu(acc2 + bias) -> LDS (bf16, same swizzled layout)
        unsigned short* lds16 = (unsigned short*)lds;
#pragma unroll
        for (int cc = 0; cc < 2; ++cc) {
            const int c = wave * 2 + cc;
            const float bc = bias[c * 16 + l16];
            const int colc = c * 16 + l16;
            const int col4 = colc >> 3;
#pragma unroll
            for (int i = 0; i < 4; ++i) {
                const int lrow = quad * 4 + i;
                lds16[LDS_SLOT(lrow, col4) * 8 + (colc & 7)] =
                    f2b(fmaxf(acc2[cc][i] + bc, 0.f));
            }
        }
    }
    __syncthreads();

    if (wave < 3) {    // out += h2 @ WotBot ; write fp32 out (40 cols)
#pragma unroll
        for (int kh = 0; kh < 4; ++kh) {
            short8 a = __builtin_bit_cast(short8, lds[LDS_SLOT(l16, quad + kh * 4)]);
            short8 b = __builtin_bit_cast(short8,
                *(const uint4*)(Wot + (size_t)(((wave * 8 + 4 + kh) * 64 + lane) * 8)));
            accO = __builtin_amdgcn_mfma_f32_16x16x32_bf16(a, b, accO, 0, 0, 0);
        }
        const int colc = wave * 16 + l16;
        if (colc < 40) {
            const float bco = bo[colc];
#pragma unroll
            for (int i = 0; i < 4; ++i) {
                int row = rowbase + quad * 4 + i;
                if (row < N) out[(size_t)row * 40 + colc] = accO[i] + bco;
            }
        }
    }
}

extern "C" void kernel_launch(void* const* d_in, const int* in_sizes, int n_in,
                              void* d_out, int out_size, void* d_ws, size_t ws_size,
                              hipStream_t stream) {
    const float* x     = (const float*)d_in[0];
    const int*   ei1   = (const int*)d_in[1];
    const int*   ei2   = (const int*)d_in[2];
    const float* wl1   = (const float*)d_in[3];
    const float* wr1   = (const float*)d_in[4];
    const float* b1    = (const float*)d_in[5];
    const float* wl2   = (const float*)d_in[6];
    const float* wr2   = (const float*)d_in[7];
    const float* b2    = (const float*)d_in[8];
    const float* w_out = (const float*)d_in[9];
    const float* b_out = (const float*)d_in[10];

    const int N  = in_sizes[0] / 128;
    const int E  = in_sizes[1] / 2;
    const int nb = (N + 255) >> 8;   // buckets of 256 dst nodes (<= MAXB)

    // ---- workspace (ints): [hist1|gcur1|hist2|gcur2]=2048 | bptr1 | bptr2 |
    //      row_ptr1 | row_ptr2 | part1 | col1 | part2 | col2 | bf16 arrays
    int* hist1    = (int*)d_ws;
    int* gcur1    = hist1 + 512;
    int* hist2    = gcur1 + 512;
    int* gcur2    = hist2 + 512;
    int* bptr1    = gcur2 + 512;
    int* bptr2    = bptr1 + 513;
    int* row_ptr1 = bptr2 + 513;
    int* row_ptr2 = row_ptr1 + (N + 1);
    int* part1    = row_ptr2 + (N + 1);
    int* col1     = part1 + E;
    int* part2    = col1 + E;
    int* col2     = part2 + E;
    int* done     = gcur2 + 511;     // inside the memset-zeroed counter region
    size_t int_cnt = (size_t)(2048 + 1026 + 2 * (N + 1)) + (size_t)4 * E;
    int_cnt = (int_cnt + 3) & ~(size_t)3;                 // 16 B align
    unsigned short* xb   = (unsigned short*)((int*)d_ws + int_cnt);
    unsigned short* h1b  = xb  + (size_t)N * 128;
    unsigned short* wt1  = h1b + (size_t)N * 128;
    unsigned short* wt2  = wt1 + 32768;
    unsigned short* wot  = wt2 + 32768;

    const long n8         = (long)N * 128 / 8;
    const int prep_blocks = (int)((n8 + 255) / 256);      // covers all prep work
    const int tile_blocks = (N + 15) / 16;

    hipMemsetAsync(hist1, 0, 2048 * sizeof(int), stream);

    prep_hist<<<prep_blocks, 256, 0, stream>>>(
        (const float4*)x, (uint4*)xb, n8, wl1, wr1, wl2, wr2, w_out,
        wt1, wt2, wot, ei1 + E, ei2 + E, hist1, hist2, bptr1, bptr2,
        done, E, nb);

    partition_edges2<<<dim3(PBLK, 2), 256, 0, stream>>>(
        ei1, ei2, bptr1, bptr2, gcur1, gcur2, part1, part2, E, nb);
    node_sort2<<<dim3(nb, 2), 256, 0, stream>>>(
        bptr1, bptr2, part1, part2, col1, col2, row_ptr1, row_ptr2, N, E);

    fused_layer1<<<tile_blocks, 256, 0, stream>>>(
        (const uint4*)xb, row_ptr1, col1, wt1, b1, h1b, N);
    fused_layer2<<<tile_blocks, 256, 0, stream>>>(
        (const uint4*)h1b, row_ptr2, col2, wt2, b2, wot, b_out,
        (float*)d_out, N);
}

// Round 10
// 380.671 us; speedup vs baseline: 1.9763x; 1.0818x over previous
//
#include <hip/hip_runtime.h>

// ---------------------------------------------------------------------------
// JK-SAGE forward. bf16 features, fp32 accumulate, MFMA bf16 GEMMs.
// MEASURED-OPTIMUM schedule (round-3 exact, 382.8 us). 6 dispatches + memset:
//   memset(counters) ; prep_hist (cast + weight repack + bucket hist)
//   bucket_scan2 ; partition_edges2 ; node_sort2
//   fused_layer1 (gather+GEMM) ; fused_layer2 (gather+GEMM+JK out)
// Edge record: src | (dst&255)<<17  (requires N <= 131072; here N = 100000).
// Session ledger (why every piece is the way it is):
//  - gather: 3.6-3.7 TB/s, FETCH ~268 MB -- invariant across 5 schedules;
//    random 256-B-row gather ceiling of the L2/L3 path. Not improvable by
//    src ordering (r6), degree-perm (r5), or edge-parallel LDS atomics (r1).
//  - build: SEPARATE bucket_scan2 dispatch beats in-kernel done-ticket scan
//    by 29 us (r9 vs r3: 512 device-fences + ticket + serialized tail).
//    Role-union chains (r7, +48us), cooperative single-kernel (r8, +370us),
//    16K-bin sort (r6, +75us), lane-0 serial flush (r4, +570us) ALL regressed.
//  - fused layers: consecutive 16-node tiles; aggb/h2b never hit HBM.
// ---------------------------------------------------------------------------

#define MAXB  512    // max buckets (N <= 131072 with 256-node buckets)
#define CAP   24     // partition LDS staging entries per bucket
#define CAPS  6144   // node_sort per-bucket record capacity (lambda=4096, 32 sigma)
#define PBLK  384    // partition grid (per layer)

typedef __attribute__((ext_vector_type(8))) short short8;
typedef __attribute__((ext_vector_type(4))) float floatx4;

__device__ __forceinline__ unsigned short f2b(float f) {
    unsigned u = __float_as_uint(f);
    unsigned r = (u + 0x7fffu + ((u >> 16) & 1u)) >> 16;   // RNE
    return (unsigned short)r;
}
__device__ __forceinline__ float lo2f(unsigned u) { return __uint_as_float(u << 16); }
__device__ __forceinline__ float hi2f(unsigned u) { return __uint_as_float(u & 0xffff0000u); }
__device__ __forceinline__ unsigned pack2(float a, float b) {
    return (unsigned)f2b(a) | ((unsigned)f2b(b) << 16);
}

// ---- fused one-time prep: cast x -> bf16, repack weights, bucket histogram
__global__ __launch_bounds__(256)
void prep_hist(const float4* __restrict__ x4, uint4* __restrict__ xb4, long n8,
               const float* __restrict__ wl1, const float* __restrict__ wr1,
               const float* __restrict__ wl2, const float* __restrict__ wr2,
               const float* __restrict__ wo,
               unsigned short* __restrict__ wt1, unsigned short* __restrict__ wt2,
               unsigned short* __restrict__ wot,
               const int* __restrict__ dst1, const int* __restrict__ dst2,
               int* __restrict__ hist1, int* __restrict__ hist2, int E, int nb) {
    long i = (long)blockIdx.x * 256 + threadIdx.x;
    if (i < n8) {                                        // cast 8 floats -> bf16
        float4 a = x4[i * 2];
        float4 b = x4[i * 2 + 1];
        uint4 o;
        o.x = pack2(a.x, a.y); o.y = pack2(a.z, a.w);
        o.z = pack2(b.x, b.y); o.w = pack2(b.z, b.w);
        xb4[i] = o;
    }
    if (i < 65536) {   // layer weights into MFMA b-frag order
        int l = (int)(i >> 15);
        int k5 = (int)(i & 32767);
        int j = k5 & 7, lane = (k5 >> 3) & 63, kb = (k5 >> 9) & 7, c = k5 >> 12;
        int k = kb * 32 + (lane >> 4) * 8 + j;
        int n = c * 16 + (lane & 15);
        const float* Wl = l ? wl2 : wl1;
        const float* Wr = l ? wr2 : wr1;
        float v = (k < 128) ? Wl[k * 128 + n] : Wr[(k - 128) * 128 + n];
        (l ? wt2 : wt1)[k5] = f2b(v);
    } else if (i < 65536 + 12288) {
        int k5 = (int)(i - 65536);
        int j = k5 & 7, lane = (k5 >> 3) & 63, kb = (k5 >> 9) & 7, c = k5 >> 12;
        int k = kb * 32 + (lane >> 4) * 8 + j;
        int col = c * 16 + (lane & 15);
        float v = (col < 40) ? wo[k * 40 + col] : 0.0f;
        wot[k5] = f2b(v);
    }
    // ---- bucket histogram (blocks 0..511; counters pre-zeroed by memset)
    __shared__ int h[MAXB];
    if (blockIdx.x < 512) {
        const int layer = blockIdx.x >> 8;
        const int bx    = blockIdx.x & 255;
        const int* dst  = layer ? dst2 : dst1;
        int* hist       = layer ? hist2 : hist1;
        for (int k = threadIdx.x; k < nb; k += 256) h[k] = 0;
        __syncthreads();
        for (int e = bx * 256 + threadIdx.x; e < E; e += 256 * 256)
            atomicAdd(&h[dst[e] >> 8], 1);
        __syncthreads();
        for (int k = threadIdx.x; k < nb; k += 256)
            if (h[k]) atomicAdd(&hist[k], h[k]);
    }
}

// ---- exclusive scan of bucket counts; blockIdx.x = layer
__global__ __launch_bounds__(256)
void bucket_scan2(const int* __restrict__ hist1, const int* __restrict__ hist2,
                  int* __restrict__ bptr1, int* __restrict__ bptr2, int nb, int E) {
    __shared__ int pair[256];
    const int* hist = blockIdx.x ? hist2 : hist1;
    int* bptr       = blockIdx.x ? bptr2 : bptr1;
    int t = threadIdx.x;
    int v0 = (2 * t < nb) ? hist[2 * t] : 0;
    int v1 = (2 * t + 1 < nb) ? hist[2 * t + 1] : 0;
    pair[t] = v0 + v1;
    __syncthreads();
    for (int off = 1; off < 256; off <<= 1) {
        int y = (t >= off) ? pair[t - off] : 0;
        __syncthreads();
        pair[t] += y;
        __syncthreads();
    }
    int ebase = pair[t] - (v0 + v1);
    if (2 * t < nb)     bptr[2 * t]     = ebase;
    if (2 * t + 1 < nb) bptr[2 * t + 1] = ebase + v0;
    if (t == 0) bptr[nb] = E;
}

// ---- partition edges into bucket regions with LDS chunk staging; dual layer
__global__ __launch_bounds__(256)
void partition_edges2(const int* __restrict__ ei1, const int* __restrict__ ei2,
                      const int* __restrict__ bptr1, const int* __restrict__ bptr2,
                      int* __restrict__ gcur1, int* __restrict__ gcur2,
                      int* __restrict__ part1, int* __restrict__ part2,
                      int E, int nb) {
    __shared__ unsigned stage[MAXB][CAP];
    __shared__ int lcnt[MAXB];
    const int* src  = blockIdx.y ? ei2 : ei1;
    const int* dst  = src + E;
    const int* bptr = blockIdx.y ? bptr2 : bptr1;
    int* gcur       = blockIdx.y ? gcur2 : gcur1;
    int* part       = blockIdx.y ? part2 : part1;
    const int t = threadIdx.x;
    for (int i = t; i < nb; i += 256) lcnt[i] = 0;
    __syncthreads();
    const int per = (E + gridDim.x - 1) / gridDim.x;
    const int e0 = blockIdx.x * per;
    const int e1 = min(e0 + per, E);
    for (int e = e0 + t; e < e1; e += 256) {
        int d = dst[e];
        int b = d >> 8;
        unsigned rec = (unsigned)src[e] | ((unsigned)(d & 255) << 17);
        int p = atomicAdd(&lcnt[b], 1);
        if (p < CAP) stage[b][p] = rec;
        else {   // staging overflow (rare): direct global write
            int g = atomicAdd(&gcur[b], 1);
            part[bptr[b] + g] = (int)rec;
        }
    }
    __syncthreads();
    for (int b = t; b < nb; b += 256) {
        int c = lcnt[b]; if (c > CAP) c = CAP;
        if (c > 0) {
            int g = atomicAdd(&gcur[b], c);
            int base = bptr[b] + g;
            for (int i = 0; i < c; ++i) part[base + i] = (int)stage[b][i];
        }
    }
}

// ---- per-bucket counting sort -> per-node CSR order; dual layer
__global__ __launch_bounds__(256)
void node_sort2(const int* __restrict__ bptr1, const int* __restrict__ bptr2,
                const int* __restrict__ part1, const int* __restrict__ part2,
                int* __restrict__ col1, int* __restrict__ col2,
                int* __restrict__ row_ptr1, int* __restrict__ row_ptr2,
                int N, int E) {
    __shared__ int recs[CAPS];
    __shared__ int sorted[CAPS];
    __shared__ int hcnt[256];
    __shared__ int hoff[256];
    const int* bptr = blockIdx.y ? bptr2 : bptr1;
    const int* part = blockIdx.y ? part2 : part1;
    int* col        = blockIdx.y ? col2 : col1;
    int* row_ptr    = blockIdx.y ? row_ptr2 : row_ptr1;
    const int b = blockIdx.x, t = threadIdx.x;
    const int beg = bptr[b], end = bptr[b + 1];
    int cnt = end - beg;
    if (cnt > CAPS) cnt = CAPS;   // statistically impossible (32 sigma margin)

    for (int i = t; i < cnt; i += 256) recs[i] = part[beg + i];
    hcnt[t] = 0;
    __syncthreads();
    for (int i = t; i < cnt; i += 256)
        atomicAdd(&hcnt[((unsigned)recs[i]) >> 17], 1);
    __syncthreads();

    int v = hcnt[t];
    hoff[t] = v;
    __syncthreads();
    for (int off = 1; off < 256; off <<= 1) {
        int y = (t >= off) ? hoff[t - off] : 0;
        __syncthreads();
        hoff[t] += y;
        __syncthreads();
    }
    int myoff = hoff[t] - v;   // exclusive prefix for local node t

    int row = b * 256 + t;
    if (row <= N) row_ptr[row] = beg + myoff;
    if (b == gridDim.x - 1 && t == 0) row_ptr[N] = E;
    __syncthreads();
    hoff[t] = myoff;
    hcnt[t] = 0;       // reuse as cursor
    __syncthreads();

    for (int i = t; i < cnt; i += 256) {
        unsigned rec = (unsigned)recs[i];
        int node = rec >> 17;
        int p = hoff[node] + atomicAdd(&hcnt[node], 1);
        sorted[p] = (int)(rec & 0x1FFFF);
    }
    __syncthreads();
    for (int i = t; i < cnt; i += 256) col[beg + i] = sorted[i];
}

// ---- proven CSR gather body: mean of xb[col[...]] into fp32 acc[8].
// 16 lanes/node, 8 row-loads in flight, col prefetch for next chunk.
__device__ __forceinline__ void gather_node(const uint4* __restrict__ xb,
                                            const int* __restrict__ col,
                                            int beg, int end, int lane,
                                            float acc[8]) {
    int e = beg;
    if (e + 8 <= end) {
        int cidx[8];
#pragma unroll
        for (int q = 0; q < 8; ++q) cidx[q] = col[e + q];
        for (;;) {
            uint4 v[8];
#pragma unroll
            for (int q = 0; q < 8; ++q) v[q] = xb[(size_t)cidx[q] * 16 + lane];
            e += 8;
            const bool more = (e + 8 <= end);
            if (more) {
#pragma unroll
                for (int q = 0; q < 8; ++q) cidx[q] = col[e + q];
            }
#pragma unroll
            for (int q = 0; q < 8; ++q) {
                acc[0] += lo2f(v[q].x); acc[1] += hi2f(v[q].x);
                acc[2] += lo2f(v[q].y); acc[3] += hi2f(v[q].y);
                acc[4] += lo2f(v[q].z); acc[5] += hi2f(v[q].z);
                acc[6] += lo2f(v[q].w); acc[7] += hi2f(v[q].w);
            }
            if (!more) break;
        }
    }
    for (; e + 3 < end; e += 4) {
        uint4 v[4];
#pragma unroll
        for (int q = 0; q < 4; ++q) v[q] = xb[(size_t)col[e + q] * 16 + lane];
#pragma unroll
        for (int q = 0; q < 4; ++q) {
            acc[0] += lo2f(v[q].x); acc[1] += hi2f(v[q].x);
            acc[2] += lo2f(v[q].y); acc[3] += hi2f(v[q].y);
            acc[4] += lo2f(v[q].z); acc[5] += hi2f(v[q].z);
            acc[6] += lo2f(v[q].w); acc[7] += hi2f(v[q].w);
        }
    }
    for (; e < end; ++e) {
        uint4 v0 = xb[(size_t)col[e] * 16 + lane];
        acc[0] += lo2f(v0.x); acc[1] += hi2f(v0.x);
        acc[2] += lo2f(v0.y); acc[3] += hi2f(v0.y);
        acc[4] += lo2f(v0.z); acc[5] += hi2f(v0.z);
        acc[6] += lo2f(v0.w); acc[7] += hi2f(v0.w);
    }
    float inv = 1.0f / fmaxf((float)(end - beg), 1.0f);
#pragma unroll
    for (int j = 0; j < 8; ++j) acc[j] *= inv;
}

// LDS tile: 16 rows x 16 uint4, slot = row*16 + (col4 ^ (row&7))  (bank swizzle)
#define LDS_SLOT(row, col4) ((row) * 16 + ((col4) ^ ((row) & 7)))

// ---- fused layer 1: gather (tile of 16 consecutive nodes -> LDS) + GEMM -> h1b
__global__ __launch_bounds__(256)
void fused_layer1(const uint4* __restrict__ xb, const int* __restrict__ row_ptr,
                  const int* __restrict__ col,
                  const unsigned short* __restrict__ Wt,  // frag-order [8][8][64][8]
                  const float* __restrict__ bias,
                  unsigned short* __restrict__ Hb, int N) {
    __shared__ uint4 lds[16 * 16];
    const int t = threadIdx.x;
    {   // gather phase: node = base + t/16, lane = t%16 (proven kernel)
        const int lrow = t >> 4;
        const int lane = t & 15;
        const int node = blockIdx.x * 16 + lrow;
        float acc[8];
#pragma unroll
        for (int j = 0; j < 8; ++j) acc[j] = 0.0f;
        if (node < N)
            gather_node(xb, col, row_ptr[node], row_ptr[node + 1], lane, acc);
        uint4 o;
        o.x = pack2(acc[0], acc[1]); o.y = pack2(acc[2], acc[3]);
        o.z = pack2(acc[4], acc[5]); o.w = pack2(acc[6], acc[7]);
        lds[LDS_SLOT(lrow, lane)] = o;
    }
    __syncthreads();

    // GEMM phase: wave w owns col-tiles {2w, 2w+1}; A rows 0..15 shared.
    const int wave = t >> 6;
    const int lane = t & 63;
    const int quad = lane >> 4;
    const int l16  = lane & 15;
    const int rowbase = blockIdx.x * 16;

    floatx4 acc2[2] = {(floatx4){0.f,0.f,0.f,0.f}, (floatx4){0.f,0.f,0.f,0.f}};
    int arow = rowbase + l16; if (arow >= N) arow = N - 1;
    const unsigned short* Xs = (const unsigned short*)xb;
    const size_t aoff = (size_t)arow * 128 + quad * 8;

#pragma unroll
    for (int kb = 0; kb < 8; ++kb) {
        short8 a;
        if (kb < 4)
            a = __builtin_bit_cast(short8, lds[LDS_SLOT(l16, quad + (kb & 3) * 4)]);
        else
            a = __builtin_bit_cast(short8, *(const uint4*)(Xs + aoff + (kb & 3) * 32));
#pragma unroll
        for (int cc = 0; cc < 2; ++cc) {
            const int c = wave * 2 + cc;
            short8 b = __builtin_bit_cast(short8,
                *(const uint4*)(Wt + (size_t)(((c * 8 + kb) * 64 + lane) * 8)));
            acc2[cc] = __builtin_amdgcn_mfma_f32_16x16x32_bf16(a, b, acc2[cc], 0, 0, 0);
        }
    }

#pragma unroll
    for (int cc = 0; cc < 2; ++cc) {
        const int c = wave * 2 + cc;
        const float bc = bias[c * 16 + l16];
#pragma unroll
        for (int i = 0; i < 4; ++i) {
            int row = rowbase + quad * 4 + i;
            if (row < N)
                Hb[(size_t)row * 128 + c * 16 + l16] = f2b(fmaxf(acc2[cc][i] + bc, 0.f));
        }
    }
}

// ---- fused layer 2: gather + GEMM + JK out. h2 lives only in regs/LDS.
__global__ __launch_bounds__(256)
void fused_layer2(const uint4* __restrict__ h1b4, const int* __restrict__ row_ptr,
                  const int* __restrict__ col,
                  const unsigned short* __restrict__ Wt,   // [8][8][64][8]
                  const float* __restrict__ bias,
                  const unsigned short* __restrict__ Wot,  // [3][8][64][8]; kb<4 = h1, kb>=4 = h2
                  const float* __restrict__ bo,
                  float* __restrict__ out, int N) {
    __shared__ uint4 lds[16 * 16];
    const int t = threadIdx.x;
    {   // gather phase (source = h1b)
        const int lrow = t >> 4;
        const int lane = t & 15;
        const int node = blockIdx.x * 16 + lrow;
        float acc[8];
#pragma unroll
        for (int j = 0; j < 8; ++j) acc[j] = 0.0f;
        if (node < N)
            gather_node(h1b4, col, row_ptr[node], row_ptr[node + 1], lane, acc);
        uint4 o;
        o.x = pack2(acc[0], acc[1]); o.y = pack2(acc[2], acc[3]);
        o.z = pack2(acc[4], acc[5]); o.w = pack2(acc[6], acc[7]);
        lds[LDS_SLOT(lrow, lane)] = o;
    }
    __syncthreads();

    const int wave = t >> 6;
    const int lane = t & 63;
    const int quad = lane >> 4;
    const int l16  = lane & 15;
    const int rowbase = blockIdx.x * 16;

    floatx4 acc2[2] = {(floatx4){0.f,0.f,0.f,0.f}, (floatx4){0.f,0.f,0.f,0.f}};
    floatx4 accO    = (floatx4){0.f,0.f,0.f,0.f};
    int arow = rowbase + l16; if (arow >= N) arow = N - 1;
    const unsigned short* H1s = (const unsigned short*)h1b4;
    const size_t aoff = (size_t)arow * 128 + quad * 8;

#pragma unroll
    for (int kb = 0; kb < 8; ++kb) {
        short8 a;
        if (kb < 4)
            a = __builtin_bit_cast(short8, lds[LDS_SLOT(l16, quad + (kb & 3) * 4)]);
        else
            a = __builtin_bit_cast(short8, *(const uint4*)(H1s + aoff + (kb & 3) * 32));
#pragma unroll
        for (int cc = 0; cc < 2; ++cc) {
            const int c = wave * 2 + cc;
            short8 b = __builtin_bit_cast(short8,
                *(const uint4*)(Wt + (size_t)(((c * 8 + kb) * 64 + lane) * 8)));
            acc2[cc] = __builtin_amdgcn_mfma_f32_16x16x32_bf16(a, b, acc2[cc], 0, 0, 0);
        }
        if (kb >= 4 && wave < 3) {   // out += h1 @ WotTop (reuse live h1 frags)
            short8 b = __builtin_bit_cast(short8,
                *(const uint4*)(Wot + (size_t)(((wave * 8 + (kb - 4)) * 64 + lane) * 8)));
            accO = __builtin_amdgcn_mfma_f32_16x16x32_bf16(a, b, accO, 0, 0, 0);
        }
    }

    __syncthreads();   // all agg-frag reads done before overwriting LDS with h2
    {   // h2 = relu(acc2 + bias) -> LDS (bf16, same swizzled layout)
        unsigned short* lds16 = (unsigned short*)lds;
#pragma unroll
        for (int cc = 0; cc < 2; ++cc) {
            const int c = wave * 2 + cc;
            const float bc = bias[c * 16 + l16];
            const int colc = c * 16 + l16;
            const int col4 = colc >> 3;
#pragma unroll
            for (int i = 0; i < 4; ++i) {
                const int lrow = quad * 4 + i;
                lds16[LDS_SLOT(lrow, col4) * 8 + (colc & 7)] =
                    f2b(fmaxf(acc2[cc][i] + bc, 0.f));
            }
        }
    }
    __syncthreads();

    if (wave < 3) {    // out += h2 @ WotBot ; write fp32 out (40 cols)
#pragma unroll
        for (int kh = 0; kh < 4; ++kh) {
            short8 a = __builtin_bit_cast(short8, lds[LDS_SLOT(l16, quad + kh * 4)]);
            short8 b = __builtin_bit_cast(short8,
                *(const uint4*)(Wot + (size_t)(((wave * 8 + 4 + kh) * 64 + lane) * 8)));
            accO = __builtin_amdgcn_mfma_f32_16x16x32_bf16(a, b, accO, 0, 0, 0);
        }
        const int colc = wave * 16 + l16;
        if (colc < 40) {
            const float bco = bo[colc];
#pragma unroll
            for (int i = 0; i < 4; ++i) {
                int row = rowbase + quad * 4 + i;
                if (row < N) out[(size_t)row * 40 + colc] = accO[i] + bco;
            }
        }
    }
}

extern "C" void kernel_launch(void* const* d_in, const int* in_sizes, int n_in,
                              void* d_out, int out_size, void* d_ws, size_t ws_size,
                              hipStream_t stream) {
    const float* x     = (const float*)d_in[0];
    const int*   ei1   = (const int*)d_in[1];
    const int*   ei2   = (const int*)d_in[2];
    const float* wl1   = (const float*)d_in[3];
    const float* wr1   = (const float*)d_in[4];
    const float* b1    = (const float*)d_in[5];
    const float* wl2   = (const float*)d_in[6];
    const float* wr2   = (const float*)d_in[7];
    const float* b2    = (const float*)d_in[8];
    const float* w_out = (const float*)d_in[9];
    const float* b_out = (const float*)d_in[10];

    const int N  = in_sizes[0] / 128;
    const int E  = in_sizes[1] / 2;
    const int nb = (N + 255) >> 8;   // buckets of 256 dst nodes (<= MAXB)

    // ---- workspace (ints): [hist1|gcur1|hist2|gcur2]=2048 | bptr1 | bptr2 |
    //      row_ptr1 | row_ptr2 | part1 | col1 | part2 | col2 | bf16 arrays
    int* hist1    = (int*)d_ws;
    int* gcur1    = hist1 + 512;
    int* hist2    = gcur1 + 512;
    int* gcur2    = hist2 + 512;
    int* bptr1    = gcur2 + 512;
    int* bptr2    = bptr1 + 513;
    int* row_ptr1 = bptr2 + 513;
    int* row_ptr2 = row_ptr1 + (N + 1);
    int* part1    = row_ptr2 + (N + 1);
    int* col1     = part1 + E;
    int* part2    = col1 + E;
    int* col2     = part2 + E;
    size_t int_cnt = (size_t)(2048 + 1026 + 2 * (N + 1)) + (size_t)4 * E;
    int_cnt = (int_cnt + 3) & ~(size_t)3;                 // 16 B align
    unsigned short* xb   = (unsigned short*)((int*)d_ws + int_cnt);
    unsigned short* h1b  = xb  + (size_t)N * 128;
    unsigned short* wt1  = h1b + (size_t)N * 128;
    unsigned short* wt2  = wt1 + 32768;
    unsigned short* wot  = wt2 + 32768;

    const long n8         = (long)N * 128 / 8;
    const int prep_blocks = (int)((n8 + 255) / 256);      // covers all prep work
    const int tile_blocks = (N + 15) / 16;

    hipMemsetAsync(hist1, 0, 2048 * sizeof(int), stream);

    prep_hist<<<prep_blocks, 256, 0, stream>>>(
        (const float4*)x, (uint4*)xb, n8, wl1, wr1, wl2, wr2, w_out,
        wt1, wt2, wot, ei1 + E, ei2 + E, hist1, hist2, E, nb);

    bucket_scan2<<<2, 256, 0, stream>>>(hist1, hist2, bptr1, bptr2, nb, E);
    partition_edges2<<<dim3(PBLK, 2), 256, 0, stream>>>(
        ei1, ei2, bptr1, bptr2, gcur1, gcur2, part1, part2, E, nb);
    node_sort2<<<dim3(nb, 2), 256, 0, stream>>>(
        bptr1, bptr2, part1, part2, col1, col2, row_ptr1, row_ptr2, N, E);

    fused_layer1<<<tile_blocks, 256, 0, stream>>>(
        (const uint4*)xb, row_ptr1, col1, wt1, b1, h1b, N);
    fused_layer2<<<tile_blocks, 256, 0, stream>>>(
        (const uint4*)h1b, row_ptr2, col2, wt2, b2, wot, b_out,
        (float*)d_out, N);
}